// Round 2
// baseline (380.869 us; speedup 1.0000x reference)
//
#include <hip/hip_runtime.h>
#include <hip/hip_fp16.h>

// GRU cell, B=65536, 256 inputs, 256 hidden, fp32 in/out.
// R2: MT=32 rows/block (33 KB LDS -> 4 blocks/CU vs 2), LDS-bounce epilogue
// so all global stores are full contiguous 1 KB/wave float4 writes (R1 showed
// 1.9x HBM write amplification from 64 B partial-line stores).

#define NHID 256
#define B_ROWS 65536
#define MT 32                       // rows per block
#define RT 2                        // row tiles per wave (MT/16)
#define GATE_STRIDE (16 * 16 * 64 * 8)  // halves per packed gate

typedef _Float16 half8 __attribute__((ext_vector_type(8)));
typedef _Float16 half4_t __attribute__((ext_vector_type(4)));
typedef float floatx4 __attribute__((ext_vector_type(4)));

// LDS layout for lx/lh: row-major [MT][256] halves, 8-half-chunk XOR swizzle
__device__ __forceinline__ int lidx(int m, int c) {
    return m * 256 + ((((c >> 3) ^ (m & 7)) << 3)) + (c & 7);
}

// ---------- weight packing: B-fragment layout for mfma_f32_16x16x32_f16 ----
// frag (gate g, coltile ct, ktile s): lane holds B[k=s*32+(lane>>4)*8+j][n=ct*16+(lane&15)]
__global__ __launch_bounds__(256) void pack_weights_kernel(
    const float* __restrict__ Wz, const float* __restrict__ Uz,
    const float* __restrict__ Wr, const float* __restrict__ Ur,
    const float* __restrict__ Wh, const float* __restrict__ Uh,
    _Float16* __restrict__ packed)
{
    int tid = blockIdx.x * blockDim.x + threadIdx.x;  // 0..49151
    int lane = tid & 63;
    int s    = (tid >> 6) & 15;
    int ct   = (tid >> 10) & 15;
    int g    = tid >> 14;  // 0:z 1:r 2:h
    const float* W = (g == 0) ? Wz : (g == 1) ? Wr : Wh;
    const float* U = (g == 0) ? Uz : (g == 1) ? Ur : Uh;
    int n  = ct * 16 + (lane & 15);
    int k0 = s * 32 + (lane >> 4) * 8;
    half8 v;
#pragma unroll
    for (int j = 0; j < 8; ++j) {
        int k = k0 + j;
        float f = (k < 256) ? W[k * 256 + n] : U[(k - 256) * 256 + n];
        v[j] = (_Float16)f;
    }
    *reinterpret_cast<half8*>(packed + (size_t)tid * 8) = v;
}

// ---------- main fused GRU kernel ----------
__global__ __launch_bounds__(256, 4) void gru_main_kernel(
    const float* __restrict__ x, const float* __restrict__ h,
    const _Float16* __restrict__ wpack,
    const float* __restrict__ bz, const float* __restrict__ br,
    const float* __restrict__ bh,
    float* __restrict__ out)
{
    // 33280 B: lx[32*256] + lh[32*256] halves (32 KB), reused as float[32][260]
    __shared__ __align__(16) unsigned char smem[MT * 260 * 4];
    _Float16* lx = reinterpret_cast<_Float16*>(smem);
    _Float16* lh = lx + MT * 256;
    float* lout = reinterpret_cast<float*>(smem);

    const int tid  = threadIdx.x;
    const int lane = tid & 63;
    const int wave = tid >> 6;        // owns coltiles wave*4 .. wave*4+3
    const int row0 = blockIdx.x * MT;
    const int m_lo = lane & 15;
    const int quad = lane >> 4;

    // ---- stage x, h -> LDS fp16 (16 outstanding 16B loads/thread) ----
    {
        const float4* xv = reinterpret_cast<const float4*>(x + (size_t)row0 * NHID);
        const float4* hv = reinterpret_cast<const float4*>(h + (size_t)row0 * NHID);
#pragma unroll
        for (int it = 0; it < (MT * 64) / 256; ++it) {
            int i = it * 256 + tid;
            int m = i >> 6;
            int c = (i & 63) * 4;
            float4 a = xv[i];
            float4 b = hv[i];
            half4_t va = { (_Float16)a.x, (_Float16)a.y, (_Float16)a.z, (_Float16)a.w };
            half4_t vb = { (_Float16)b.x, (_Float16)b.y, (_Float16)b.z, (_Float16)b.w };
            *reinterpret_cast<half4_t*>(&lx[lidx(m, c)]) = va;
            *reinterpret_cast<half4_t*>(&lh[lidx(m, c)]) = vb;
        }
    }
    __syncthreads();

    const _Float16* wz = wpack;
    const _Float16* wr = wpack + GATE_STRIDE;
    const _Float16* wh = wpack + 2 * GATE_STRIDE;

    // ---- pass 1: Sz = [x|h]@[Wz;Uz], Sr = [x|h]@[Wr;Ur]  (K=512) ----
    floatx4 accz[4][RT];
    floatx4 accr[4][RT];
#pragma unroll
    for (int c = 0; c < 4; ++c)
#pragma unroll
        for (int rt = 0; rt < RT; ++rt) {
            accz[c][rt] = (floatx4){0.f, 0.f, 0.f, 0.f};
            accr[c][rt] = (floatx4){0.f, 0.f, 0.f, 0.f};
        }

    const int mx = m_lo & 7;
#pragma unroll
    for (int s = 0; s < 16; ++s) {
        const _Float16* asrc = (s < 8) ? lx : lh;
        const int kcx = (((s & 7) * 4 + quad) ^ mx) << 3;
        half8 af[RT];
#pragma unroll
        for (int rt = 0; rt < RT; ++rt)
            af[rt] = *reinterpret_cast<const half8*>(&asrc[(rt * 16 + m_lo) * 256 + kcx]);
#pragma unroll
        for (int c = 0; c < 4; ++c) {
            const int ct = wave * 4 + c;
            half8 bzf = *reinterpret_cast<const half8*>(&wz[(size_t)((ct * 16 + s) * 64 + lane) * 8]);
            half8 brf = *reinterpret_cast<const half8*>(&wr[(size_t)((ct * 16 + s) * 64 + lane) * 8]);
#pragma unroll
            for (int rt = 0; rt < RT; ++rt) {
                accz[c][rt] = __builtin_amdgcn_mfma_f32_16x16x32_f16(af[rt], bzf, accz[c][rt], 0, 0, 0);
                accr[c][rt] = __builtin_amdgcn_mfma_f32_16x16x32_f16(af[rt], brf, accr[c][rt], 0, 0, 0);
            }
        }
    }

    __syncthreads();  // all waves done reading lh before overwriting with r*h

    // ---- epilogue 1: z, r; lh <- r*h; keep z*h and (1-z) in regs ----
    // C layout: col(tile) = lane&15, row(tile) = quad*4 + reg
#pragma unroll
    for (int c = 0; c < 4; ++c) {
        const int col = wave * 64 + c * 16 + m_lo;
        const float bzv = bz[col];
        const float brv = br[col];
#pragma unroll
        for (int rt = 0; rt < RT; ++rt) {
#pragma unroll
            for (int e = 0; e < 4; ++e) {
                const int row = rt * 16 + quad * 4 + e;
                float sz = accz[c][rt][e] + bzv;
                float sr = accr[c][rt][e] + brv;
                float zv = 1.f / (1.f + __expf(-sz));
                float rv = 1.f / (1.f + __expf(-sr));
                const int li = lidx(row, col);
                float hval = (float)lh[li];
                lh[li] = (_Float16)(rv * hval);
                accz[c][rt][e] = zv * hval;  // z*h
                accr[c][rt][e] = 1.f - zv;   // 1-z
            }
        }
    }
    __syncthreads();  // r*h visible to all waves

    // ---- pass 2: Sh = [x|r*h]@[Wh;Uh]  (K=512) ----
    floatx4 acch[4][RT];
#pragma unroll
    for (int c = 0; c < 4; ++c)
#pragma unroll
        for (int rt = 0; rt < RT; ++rt)
            acch[c][rt] = (floatx4){0.f, 0.f, 0.f, 0.f};

#pragma unroll
    for (int s = 0; s < 16; ++s) {
        const _Float16* asrc = (s < 8) ? lx : lh;
        const int kcx = (((s & 7) * 4 + quad) ^ mx) << 3;
        half8 af[RT];
#pragma unroll
        for (int rt = 0; rt < RT; ++rt)
            af[rt] = *reinterpret_cast<const half8*>(&asrc[(rt * 16 + m_lo) * 256 + kcx]);
#pragma unroll
        for (int c = 0; c < 4; ++c) {
            const int ct = wave * 4 + c;
            half8 bhf = *reinterpret_cast<const half8*>(&wh[(size_t)((ct * 16 + s) * 64 + lane) * 8]);
#pragma unroll
            for (int rt = 0; rt < RT; ++rt)
                acch[c][rt] = __builtin_amdgcn_mfma_f32_16x16x32_f16(af[rt], bhf, acch[c][rt], 0, 0, 0);
        }
    }
    __syncthreads();  // everyone done reading lx/lh before lout overwrite

    // ---- epilogue 2: h_t = z*h + (1-z)*tanh(Sh+bh) -> LDS float tile ----
#pragma unroll
    for (int c = 0; c < 4; ++c) {
        const int col = wave * 64 + c * 16 + m_lo;
        const float bhv = bh[col];
#pragma unroll
        for (int rt = 0; rt < RT; ++rt) {
#pragma unroll
            for (int e = 0; e < 4; ++e) {
                const int row = rt * 16 + quad * 4 + e;
                float sh = acch[c][rt][e] + bhv;
                float e2 = __expf(2.f * sh);
                float hh = 1.f - 2.f / (e2 + 1.f);  // tanh
                lout[row * 260 + col] = accz[c][rt][e] + accr[c][rt][e] * hh;
            }
        }
    }
    __syncthreads();

    // ---- store: contiguous 1 KB/wave float4 writes, duplicated (h_t, h_t) ----
    const size_t OUT2 = (size_t)B_ROWS * NHID;
#pragma unroll
    for (int it = 0; it < (MT * 64) / 256; ++it) {
        int i = it * 256 + tid;
        int m = i >> 6;
        int cv = (i & 63) * 4;
        float4 v = *reinterpret_cast<const float4*>(&lout[m * 260 + cv]);
        size_t idx = (size_t)(row0 + m) * NHID + cv;
        *reinterpret_cast<float4*>(&out[idx]) = v;
        *reinterpret_cast<float4*>(&out[OUT2 + idx]) = v;
    }
}

extern "C" void kernel_launch(void* const* d_in, const int* in_sizes, int n_in,
                              void* d_out, int out_size, void* d_ws, size_t ws_size,
                              hipStream_t stream) {
    (void)in_sizes; (void)n_in; (void)out_size; (void)ws_size;
    const float* x  = (const float*)d_in[0];
    const float* h  = (const float*)d_in[1];
    const float* Wz = (const float*)d_in[2];
    const float* Uz = (const float*)d_in[3];
    const float* bz = (const float*)d_in[4];
    const float* Wr = (const float*)d_in[5];
    const float* Ur = (const float*)d_in[6];
    const float* br = (const float*)d_in[7];
    const float* Wh = (const float*)d_in[8];
    const float* Uh = (const float*)d_in[9];
    const float* bh = (const float*)d_in[10];
    float* out = (float*)d_out;
    _Float16* wpack = (_Float16*)d_ws;  // 3*512*256*2 = 768 KB

    pack_weights_kernel<<<192, 256, 0, stream>>>(Wz, Uz, Wr, Ur, Wh, Uh, wpack);
    gru_main_kernel<<<B_ROWS / MT, 256, 0, stream>>>(x, h, wpack, bz, br, bh, out);
}

// Round 3
// 325.310 us; speedup vs baseline: 1.1708x; 1.1708x over previous
//
#include <hip/hip_runtime.h>
#include <hip/hip_fp16.h>

// GRU cell, B=65536, 256 inputs, 256 hidden, fp32 in/out.
// R3: 512-thread blocks (8 waves), MT=64 rows -> weight L2 re-read halved vs
// MT=32 (786 MB total), 65 KB LDS -> 2 blocks/CU = 16 waves/CU. Pass-2
// register diet: z*h and (1-z) carried as packed fp16 half2 (32 VGPRs not 64)
// so peak pressure ~105 and NO spills (R2's launch_bounds(256,4) forced 64
// VGPRs -> spill traffic +54MB fetch/+105MB write, regressed). Keep R2's
// LDS-bounce epilogue for full-line 1KB/wave stores.

#define NHID 256
#define B_ROWS 65536
#define MT 64                        // rows per block
#define RT 4                         // row tiles per wave (MT/16)
#define CPW 2                        // coltiles per wave (16 coltiles / 8 waves)
#define GATE_STRIDE (16 * 16 * 64 * 8)   // halves per packed gate

typedef _Float16 half8 __attribute__((ext_vector_type(8)));
typedef _Float16 half4_t __attribute__((ext_vector_type(4)));
typedef _Float16 half2_t __attribute__((ext_vector_type(2)));
typedef float floatx4 __attribute__((ext_vector_type(4)));

// LDS layout for lx/lh: row-major [MT][256] halves, 8-half-chunk XOR swizzle
__device__ __forceinline__ int lidx(int m, int c) {
    return m * 256 + ((((c >> 3) ^ (m & 7)) << 3)) + (c & 7);
}

// ---------- weight packing: B-fragment layout for mfma_f32_16x16x32_f16 ----
// frag (gate g, coltile ct, ktile s): lane holds B[k=s*32+(lane>>4)*8+j][n=ct*16+(lane&15)]
__global__ __launch_bounds__(256) void pack_weights_kernel(
    const float* __restrict__ Wz, const float* __restrict__ Uz,
    const float* __restrict__ Wr, const float* __restrict__ Ur,
    const float* __restrict__ Wh, const float* __restrict__ Uh,
    _Float16* __restrict__ packed)
{
    int tid = blockIdx.x * blockDim.x + threadIdx.x;  // 0..49151
    int lane = tid & 63;
    int s    = (tid >> 6) & 15;
    int ct   = (tid >> 10) & 15;
    int g    = tid >> 14;  // 0:z 1:r 2:h
    const float* W = (g == 0) ? Wz : (g == 1) ? Wr : Wh;
    const float* U = (g == 0) ? Uz : (g == 1) ? Ur : Uh;
    int n  = ct * 16 + (lane & 15);
    int k0 = s * 32 + (lane >> 4) * 8;
    half8 v;
#pragma unroll
    for (int j = 0; j < 8; ++j) {
        int k = k0 + j;
        float f = (k < 256) ? W[k * 256 + n] : U[(k - 256) * 256 + n];
        v[j] = (_Float16)f;
    }
    *reinterpret_cast<half8*>(packed + (size_t)tid * 8) = v;
}

// ---------- main fused GRU kernel ----------
__global__ __launch_bounds__(512, 2) void gru_main_kernel(
    const float* __restrict__ x, const float* __restrict__ h,
    const _Float16* __restrict__ wpack,
    const float* __restrict__ bz, const float* __restrict__ br,
    const float* __restrict__ bh,
    float* __restrict__ out)
{
    // 66560 B: lx[64*256] + lh[64*256] halves (64 KB); whole region reused
    // as float lout[64][260] for the bounce-store.
    __shared__ __align__(16) unsigned char smem[MT * 260 * 4];
    _Float16* lx = reinterpret_cast<_Float16*>(smem);
    _Float16* lh = lx + MT * 256;
    float* lout = reinterpret_cast<float*>(smem);

    const int tid  = threadIdx.x;
    const int lane = tid & 63;
    const int wave = tid >> 6;        // 0..7, owns coltiles wave*2, wave*2+1
    const int row0 = blockIdx.x * MT;
    const int m_lo = lane & 15;
    const int quad = lane >> 4;

    // ---- stage x, h -> LDS fp16 (16 outstanding 16B loads/thread) ----
    {
        const float4* xv = reinterpret_cast<const float4*>(x + (size_t)row0 * NHID);
        const float4* hv = reinterpret_cast<const float4*>(h + (size_t)row0 * NHID);
#pragma unroll
        for (int it = 0; it < (MT * 64) / 512; ++it) {
            int i = it * 512 + tid;
            int m = i >> 6;
            int c = (i & 63) * 4;
            float4 a = xv[i];
            float4 b = hv[i];
            half4_t va = { (_Float16)a.x, (_Float16)a.y, (_Float16)a.z, (_Float16)a.w };
            half4_t vb = { (_Float16)b.x, (_Float16)b.y, (_Float16)b.z, (_Float16)b.w };
            *reinterpret_cast<half4_t*>(&lx[lidx(m, c)]) = va;
            *reinterpret_cast<half4_t*>(&lh[lidx(m, c)]) = vb;
        }
    }
    __syncthreads();

    const _Float16* wz = wpack;
    const _Float16* wr = wpack + GATE_STRIDE;
    const _Float16* wh = wpack + 2 * GATE_STRIDE;

    const int mx = m_lo & 7;

    // packed (z*h, 1-z) per output element, fp16x2 -> 32 VGPRs
    half2_t zpk[CPW][RT][4];

    // ---- pass 1: Sz = [x|h]@[Wz;Uz], Sr = [x|h]@[Wr;Ur]  (K=512) ----
    {
        floatx4 accz[CPW][RT];
        floatx4 accr[CPW][RT];
#pragma unroll
        for (int c = 0; c < CPW; ++c)
#pragma unroll
            for (int rt = 0; rt < RT; ++rt) {
                accz[c][rt] = (floatx4){0.f, 0.f, 0.f, 0.f};
                accr[c][rt] = (floatx4){0.f, 0.f, 0.f, 0.f};
            }

#pragma unroll
        for (int s = 0; s < 16; ++s) {
            const _Float16* asrc = (s < 8) ? lx : lh;
            const int kcx = (((s & 7) * 4 + quad) ^ mx) << 3;
            half8 af[RT];
#pragma unroll
            for (int rt = 0; rt < RT; ++rt)
                af[rt] = *reinterpret_cast<const half8*>(&asrc[(rt * 16 + m_lo) * 256 + kcx]);
#pragma unroll
            for (int c = 0; c < CPW; ++c) {
                const int ct = wave * CPW + c;
                half8 bzf = *reinterpret_cast<const half8*>(&wz[(size_t)((ct * 16 + s) * 64 + lane) * 8]);
                half8 brf = *reinterpret_cast<const half8*>(&wr[(size_t)((ct * 16 + s) * 64 + lane) * 8]);
#pragma unroll
                for (int rt = 0; rt < RT; ++rt) {
                    accz[c][rt] = __builtin_amdgcn_mfma_f32_16x16x32_f16(af[rt], bzf, accz[c][rt], 0, 0, 0);
                    accr[c][rt] = __builtin_amdgcn_mfma_f32_16x16x32_f16(af[rt], brf, accr[c][rt], 0, 0, 0);
                }
            }
        }

        __syncthreads();  // all waves done reading lh before overwriting with r*h

        // ---- epilogue 1: z, r; lh <- r*h; zpk <- (fp16)(z*h, 1-z) ----
        // C layout: col(tile) = lane&15, row(tile) = quad*4 + reg
#pragma unroll
        for (int c = 0; c < CPW; ++c) {
            const int col = (wave * CPW + c) * 16 + m_lo;
            const float bzv = bz[col];
            const float brv = br[col];
#pragma unroll
            for (int rt = 0; rt < RT; ++rt) {
#pragma unroll
                for (int e = 0; e < 4; ++e) {
                    const int row = rt * 16 + quad * 4 + e;
                    float sz = accz[c][rt][e] + bzv;
                    float sr = accr[c][rt][e] + brv;
                    float zv = 1.f / (1.f + __expf(-sz));
                    float rv = 1.f / (1.f + __expf(-sr));
                    const int li = lidx(row, col);
                    float hval = (float)lh[li];
                    lh[li] = (_Float16)(rv * hval);
                    zpk[c][rt][e] = half2_t{ (_Float16)(zv * hval), (_Float16)(1.f - zv) };
                }
            }
        }
    }
    __syncthreads();  // r*h visible to all waves

    // ---- pass 2: Sh = [x|r*h]@[Wh;Uh]  (K=512) ----
    floatx4 acch[CPW][RT];
#pragma unroll
    for (int c = 0; c < CPW; ++c)
#pragma unroll
        for (int rt = 0; rt < RT; ++rt)
            acch[c][rt] = (floatx4){0.f, 0.f, 0.f, 0.f};

#pragma unroll
    for (int s = 0; s < 16; ++s) {
        const _Float16* asrc = (s < 8) ? lx : lh;
        const int kcx = (((s & 7) * 4 + quad) ^ mx) << 3;
        half8 af[RT];
#pragma unroll
        for (int rt = 0; rt < RT; ++rt)
            af[rt] = *reinterpret_cast<const half8*>(&asrc[(rt * 16 + m_lo) * 256 + kcx]);
#pragma unroll
        for (int c = 0; c < CPW; ++c) {
            const int ct = wave * CPW + c;
            half8 bhf = *reinterpret_cast<const half8*>(&wh[(size_t)((ct * 16 + s) * 64 + lane) * 8]);
#pragma unroll
            for (int rt = 0; rt < RT; ++rt)
                acch[c][rt] = __builtin_amdgcn_mfma_f32_16x16x32_f16(af[rt], bhf, acch[c][rt], 0, 0, 0);
        }
    }
    __syncthreads();  // everyone done reading lx/lh before lout overwrite

    // ---- epilogue 2: h_t = z*h + (1-z)*tanh(Sh+bh) -> LDS float tile ----
#pragma unroll
    for (int c = 0; c < CPW; ++c) {
        const int col = (wave * CPW + c) * 16 + m_lo;
        const float bhv = bh[col];
#pragma unroll
        for (int rt = 0; rt < RT; ++rt) {
#pragma unroll
            for (int e = 0; e < 4; ++e) {
                const int row = rt * 16 + quad * 4 + e;
                float sh = acch[c][rt][e] + bhv;
                float e2 = __expf(2.f * sh);
                float hh = 1.f - 2.f / (e2 + 1.f);  // tanh
                float zh  = (float)zpk[c][rt][e][0];
                float omz = (float)zpk[c][rt][e][1];
                lout[row * 260 + col] = zh + omz * hh;
            }
        }
    }
    __syncthreads();

    // ---- store: contiguous 1 KB/wave float4 writes, duplicated (h_t, h_t) ----
    const size_t OUT2 = (size_t)B_ROWS * NHID;
#pragma unroll
    for (int it = 0; it < (MT * 64) / 512; ++it) {
        int i = it * 512 + tid;
        int m = i >> 6;
        int cv = (i & 63) * 4;
        float4 v = *reinterpret_cast<const float4*>(&lout[m * 260 + cv]);
        size_t idx = (size_t)(row0 + m) * NHID + cv;
        *reinterpret_cast<float4*>(&out[idx]) = v;
        *reinterpret_cast<float4*>(&out[OUT2 + idx]) = v;
    }
}

extern "C" void kernel_launch(void* const* d_in, const int* in_sizes, int n_in,
                              void* d_out, int out_size, void* d_ws, size_t ws_size,
                              hipStream_t stream) {
    (void)in_sizes; (void)n_in; (void)out_size; (void)ws_size;
    const float* x  = (const float*)d_in[0];
    const float* h  = (const float*)d_in[1];
    const float* Wz = (const float*)d_in[2];
    const float* Uz = (const float*)d_in[3];
    const float* bz = (const float*)d_in[4];
    const float* Wr = (const float*)d_in[5];
    const float* Ur = (const float*)d_in[6];
    const float* br = (const float*)d_in[7];
    const float* Wh = (const float*)d_in[8];
    const float* Uh = (const float*)d_in[9];
    const float* bh = (const float*)d_in[10];
    float* out = (float*)d_out;
    _Float16* wpack = (_Float16*)d_ws;  // 3*512*256*2 = 768 KB

    pack_weights_kernel<<<192, 256, 0, stream>>>(Wz, Uz, Wr, Ur, Wh, Uh, wpack);
    gru_main_kernel<<<B_ROWS / MT, 512, 0, stream>>>(x, h, wpack, bz, br, bh, out);
}